// Round 12
// baseline (411.388 us; speedup 1.0000x reference)
//
#include <hip/hip_runtime.h>

// x(8,64,8,64,64) fp32, w_q(32,64), w_kv(64,64)
// f = d*8+n (256), p = y*64+xi (4096), p2 = y2*32+x2 (1024)

typedef __attribute__((ext_vector_type(8))) short short8;
typedef __attribute__((ext_vector_type(4))) float floatx4;
typedef __attribute__((ext_vector_type(2))) unsigned uintx2;
typedef __attribute__((ext_vector_type(4))) unsigned uintx4;

__device__ __forceinline__ short f2bf(float f) {  // RNE, finite only
    unsigned u = __builtin_bit_cast(unsigned, f);
    u += 0x7fffu + ((u >> 16) & 1u);
    return (short)(u >> 16);
}
__device__ __forceinline__ unsigned pack2bf(float a, float b) {
    return (unsigned)(unsigned short)f2bf(a) | ((unsigned)(unsigned short)f2bf(b) << 16);
}
__device__ __forceinline__ unsigned cvtpk_bf16(float lo, float hi) {
    unsigned r;
    asm("v_cvt_pk_bf16_f32 %0, %1, %2" : "=v"(r) : "v"(lo), "v"(hi));
    return r;
}

// ---------------- Fused projection: q (normalized), k (normalized), v ----------------
// R1 structure (no spill). R11: group swizzle g->dg*8+(j^dg) on q/k pack (conflicts 7.5e6->4.1e6,
// 61->54us). R12 adds:
//  (C) q-pack dword-slot swizzle: short n stored at slot n^(xc&6) -> bank gains (xc>>1)&3 ->
//      32 distinct banks, conflict-free q-pack (was ~4-way: within a wave n>>1 is constant).
//      Flush un-permutes dwords with out[d]=v[d^it] — COMPILE-TIME since r>>3==it there.
//      qraw bytes identical.
//  (D) cc-tile global loads prefetched into xreg[4] during previous tile's compute (R9's
//      attn pattern): HBM latency no longer exposed between the two staging barriers.
// No launch_bounds / overlay-pointer / packed-store changes (R2-R5 allocator blowups).
// R7 note: kv MUST be gated on (y&1)==0 (::2-subsampled rows).
// grid 512 = (b, y); thread t: n=t>>5, dg=(t>>3)&3 (d=dg*8+j), xc=t&7 (xi=xc*4+i within half)
__global__ __launch_bounds__(256) void proj(const float* __restrict__ x,
                                            const float* __restrict__ wq,
                                            const float* __restrict__ wkv,
                                            short* __restrict__ qraw,
                                            short* __restrict__ kraw,
                                            short* __restrict__ vraw) {
    int b = blockIdx.x >> 6, y = blockIdx.x & 63;
    int t = threadIdx.x;
    int n = t >> 5, dg = (t >> 3) & 3, xc = t & 7;
    bool kv = (y & 1) == 0;
    int y2 = y >> 1;

    __shared__ __align__(16) float wq_s[64 * 32];   // [c][d]
    __shared__ __align__(16) float wkv_s[64 * 64];  // [c][e]
    __shared__ __align__(16) float xs[128 * 36];    // [c16*n8][32xi + pad]; overlaid by q_lds
    __shared__ __align__(16) short k_lds[16 * 264];
    __shared__ __align__(16) short v_lds[256 * 16]; // [f][xi2]
    __shared__ float red[32 * 33];
    __shared__ float nrm[32];
    short* q_lds = (short*)xs;                      // 16896 B <= 18432 B

    for (int i = t; i < 2048; i += 256) { int d = i >> 6, c = i & 63; wq_s[c * 32 + d] = wq[i]; }
    for (int i = t; i < 4096; i += 256) { int e = i >> 6, c = i & 63; wkv_s[c * 64 + e] = wkv[i]; }
    const float* xb = x + (size_t)b * 2097152 + y * 64;   // batch stride c*n*h*w
    int ns = n ^ (xc & 6);   // q-pack dword-slot swizzle (bit0 of n preserved)

    for (int xh = 0; xh < 2; ++xh) {
        float qa[8][4], ka[8][2], va[8][2];
#pragma unroll
        for (int j = 0; j < 8; ++j) {
            qa[j][0] = qa[j][1] = qa[j][2] = qa[j][3] = 0.f;
            ka[j][0] = ka[j][1] = 0.f; va[j][0] = va[j][1] = 0.f;
        }
        float4 xreg[4];
        // prologue: load tile cc=0 into regs (latency exposed once per xh)
#pragma unroll
        for (int it = 0; it < 4; ++it) {
            int i = it * 256 + t, cn = i >> 3, e = i & 7;
            xreg[it] = *(const float4*)(xb + (size_t)(cn >> 3) * 32768 + (cn & 7) * 4096 + xh * 32 + e * 4);
        }
        for (int cc = 0; cc < 4; ++cc) {
            __syncthreads();   // prior-phase xs reads done
#pragma unroll
            for (int it = 0; it < 4; ++it) {
                int i = it * 256 + t, cn = i >> 3, e = i & 7;
                *(float4*)(xs + cn * 36 + e * 4) = xreg[it];
            }
            __syncthreads();
            // prefetch next tile during compute (commit next iteration; WAR-safe: stores above
            // consumed xreg at issue)
            if (cc < 3) {
#pragma unroll
                for (int it = 0; it < 4; ++it) {
                    int i = it * 256 + t, cn = i >> 3, e = i & 7;
                    xreg[it] = *(const float4*)(xb + (size_t)((cc + 1) * 16 + (cn >> 3)) * 32768 + (cn & 7) * 4096 + xh * 32 + e * 4);
                }
            }
            for (int c = 0; c < 16; ++c) {
                float4 xv = *(const float4*)(xs + (c * 8 + n) * 36 + xc * 4);
                float xw[4] = {xv.x, xv.y, xv.z, xv.w};
                int cg = cc * 16 + c;
                float4 wqa = *(const float4*)(wq_s + cg * 32 + dg * 8);
                float4 wqb = *(const float4*)(wq_s + cg * 32 + dg * 8 + 4);
                float wj[8] = {wqa.x, wqa.y, wqa.z, wqa.w, wqb.x, wqb.y, wqb.z, wqb.w};
#pragma unroll
                for (int j = 0; j < 8; ++j)
#pragma unroll
                    for (int i2 = 0; i2 < 4; ++i2) qa[j][i2] += wj[j] * xw[i2];
                if (kv) {
                    float4 wka = *(const float4*)(wkv_s + cg * 64 + dg * 8);
                    float4 wkb = *(const float4*)(wkv_s + cg * 64 + dg * 8 + 4);
                    float4 wva = *(const float4*)(wkv_s + cg * 64 + 32 + dg * 8);
                    float4 wvb = *(const float4*)(wkv_s + cg * 64 + 32 + dg * 8 + 4);
                    float wk[8] = {wka.x, wka.y, wka.z, wka.w, wkb.x, wkb.y, wkb.z, wkb.w};
                    float wv2[8] = {wva.x, wva.y, wva.z, wva.w, wvb.x, wvb.y, wvb.z, wvb.w};
#pragma unroll
                    for (int j = 0; j < 8; ++j) {
                        ka[j][0] += wk[j] * xw[0]; ka[j][1] += wk[j] * xw[2];
                        va[j][0] += wv2[j] * xw[0]; va[j][1] += wv2[j] * xw[2];
                    }
                }
            }
        }
        // ---- q: row-l2norm over f, pack bf16 (group+slot swizzled) via LDS, coalesced flush ----
        __syncthreads();   // all reads of xs done (q_lds overlays xs)
#pragma unroll
        for (int i2 = 0; i2 < 4; ++i2) {
            float s = 0.f;
#pragma unroll
            for (int j = 0; j < 8; ++j) s += qa[j][i2] * qa[j][i2];
            red[(xc * 4 + i2) * 33 + n * 4 + dg] = s;
        }
        __syncthreads();
        if (t < 32) {
            float s = 0.f;
            for (int k = 0; k < 32; ++k) s += red[t * 33 + k];
            nrm[t] = 1.f / fmaxf(sqrtf(s), 1e-12f);
        }
        __syncthreads();
#pragma unroll
        for (int i2 = 0; i2 < 4; ++i2) {
            float sc = nrm[xc * 4 + i2];
#pragma unroll
            for (int j = 0; j < 8; ++j)
                q_lds[(xc * 4 + i2) * 264 + (dg * 8 + (j ^ dg)) * 8 + ns] = f2bf(qa[j][i2] * sc);
        }
        __syncthreads();
        {
            size_t qg = ((size_t)b * 4096 + y * 64 + xh * 32) * 256;
#pragma unroll
            for (int it = 0; it < 4; ++it) {
                int r = it * 8 + (t >> 5), sg = t & 31;
                uintx4 v = *(const uintx4*)(q_lds + r * 264 + (sg ^ ((sg >> 3) & 3)) * 8);
                uintx4 o;   // un-permute dwords: LDS dword d holds original d^c2, c2=(r>>3)&3==it
                o[0] = v[0 ^ it]; o[1] = v[1 ^ it]; o[2] = v[2 ^ it]; o[3] = v[3 ^ it];
                *(uintx4*)(qraw + qg + (size_t)r * 256 + sg * 8) = o;
            }
        }
        // ---- k (col-l2norm over f) and v ----
        if (kv) {
            __syncthreads();
#pragma unroll
            for (int ii = 0; ii < 2; ++ii) {
                float s = 0.f;
#pragma unroll
                for (int j = 0; j < 8; ++j) s += ka[j][ii] * ka[j][ii];
                red[(xc * 2 + ii) * 33 + n * 4 + dg] = s;
            }
            __syncthreads();
            if (t < 16) {
                float s = 0.f;
                for (int k = 0; k < 32; ++k) s += red[t * 33 + k];
                nrm[t] = 1.f / fmaxf(sqrtf(s), 1e-12f);
            }
            __syncthreads();
#pragma unroll
            for (int ii = 0; ii < 2; ++ii) {
                float sc = nrm[xc * 2 + ii];
#pragma unroll
                for (int j = 0; j < 8; ++j) {
                    int f = (dg * 8 + j) * 8 + n;
                    k_lds[(xc * 2 + ii) * 264 + (dg * 8 + (j ^ dg)) * 8 + n] = f2bf(ka[j][ii] * sc);
                    v_lds[f * 16 + xc * 2 + ii] = f2bf(va[j][ii]);
                }
            }
            __syncthreads();
            size_t kg = ((size_t)b * 1024 + y2 * 32 + xh * 16) * 256;
#pragma unroll
            for (int it = 0; it < 2; ++it) {
                int r = it * 8 + (t >> 5), sg = t & 31;
                *(uint4*)(kraw + kg + (size_t)r * 256 + sg * 8) =
                    *(const uint4*)(k_lds + r * 264 + (sg ^ ((sg >> 3) & 3)) * 8);
            }
            size_t vg = (size_t)b * 262144 + (size_t)y2 * 32 + xh * 16;
#pragma unroll
            for (int it = 0; it < 2; ++it) {
                int idx = it * 256 + t, f = idx >> 1, hh = idx & 1;
                *(uint4*)(vraw + vg + (size_t)f * 1024 + hh * 8) = *(const uint4*)(v_lds + f * 16 + hh * 8);
            }
        }
    }
}

// ---------------- attn: qtile=128, 8 waves; P software-pipelined, ONE barrier/kc ----------------
// R9 text (best measured attn). Window: commit(kc+1) -> issue prefetch(kc+2) -> phase1(kc) ->
// phase2(kc-1) -> barrier; prefetch loads get phase1+phase2 (~3K cy) to land before the
// barrier's vmcnt(0) drain. v_s triple-buffered; k_s/p_s double. XCD swizzle b=bid&7.
// grid 256 = (b, qt of 128 rows), 512 threads; LDS ~114KB, 1 block/CU.
// phase1: wave (kt=wv&1, pp=wv>>1): S^T rows kt*16..+16, cols pp*32..+32
// phase2: wave (fh=wv&3, ph=wv>>2): out^T f [fh*64,+64), p [ph*64,+64)
// LDS col-slot swizzles (write and read sides must match):
//   k_s: slot c=fs*4+quad stored at c^((c>>3)&1)  (write: j^((kseg>>2)&1))
//   v_s: slot quad stored at quad^((row>>3)&1)    (write: j^((t>>4)&1))
__global__ __launch_bounds__(512, 2) void attn(const short* __restrict__ qraw,
                                               const short* __restrict__ kraw,
                                               const short* __restrict__ vraw,
                                               float* __restrict__ out) {
    int b = blockIdx.x & 7, qt = blockIdx.x >> 3;   // XCD swizzle: batch pinned to one XCD
    int t = threadIdx.x, wv = t >> 6, lane = t & 63, l16 = lane & 15, quad = lane >> 4;

    __shared__ __align__(16) short k_s[2][32 * 264];  // [kp][f]+pad, 2x16.9KB
    __shared__ __align__(16) short v_s[3][256 * 40];  // [f][kp]+pad, 3x20.5KB (triple: see hdr)
    __shared__ __align__(16) short p_s[2][128 * 40];  // [p][kp]+pad, 2x10.25KB
    __shared__ float dsum[2][128];

    int kt = wv & 1, pp = wv >> 1;    // phase-1 role
    int fh = wv & 3, ph = wv >> 2;    // phase-2 role

    // Q fragments (prenormalized): wave's phase-1 p = qt*128 + pp*32 + pt*16 + l16
    short8 qf[2][8];
    const short* qb = qraw + ((size_t)b * 4096 + qt * 128 + pp * 32) * 256;
#pragma unroll
    for (int pt = 0; pt < 2; ++pt)
#pragma unroll
        for (int fs = 0; fs < 8; ++fs)
            qf[pt][fs] = *(const short8*)(qb + (pt * 16 + l16) * 256 + fs * 32 + quad * 8);

    floatx4 acc[4][4];  // [p-tile of 16 within ph*64][f-tile of 16 within fh*64]
#pragma unroll
    for (int i = 0; i < 4; ++i)
#pragma unroll
        for (int j = 0; j < 4; ++j) acc[i][j] = (floatx4){0.f, 0.f, 0.f, 0.f};
    float dacc0 = 0.f, dacc1 = 0.f;

    // staging: K chunk 32x256, V chunk 256x32, 16 shorts (2 x b128) per thread each
    int krow = t >> 4, kseg = t & 15;
    int vrow = t >> 1, vhalf = t & 1;
    int sk = (kseg >> 2) & 1, sv = (t >> 4) & 1;
    const short* kbase = kraw + ((size_t)b * 1024 + krow) * 256 + kseg * 16;
    const short* vbase = vraw + ((size_t)b * 256 + vrow) * 1024 + vhalf * 16;

    short8 kst[2], vst[2];
    // stage chunk 0 into k_s[0]/v_s[0] (with swizzle)
#pragma unroll
    for (int j = 0; j < 2; ++j) {
        kst[j] = *(const short8*)(kbase + j * 8);
        vst[j] = *(const short8*)(vbase + j * 8);
    }
#pragma unroll
    for (int j = 0; j < 2; ++j) {
        *(short8*)(k_s[0] + krow * 264 + kseg * 16 + (j ^ sk) * 8) = kst[j];
        *(short8*)(v_s[0] + vrow * 40 + vhalf * 16 + (j ^ sv) * 8) = vst[j];
    }
    // prefetch chunk 1 into regs
#pragma unroll
    for (int j = 0; j < 2; ++j) {
        kst[j] = *(const short8*)(kbase + 8192 + j * 8);
        vst[j] = *(const short8*)(vbase + 32 + j * 8);
    }
    __syncthreads();

    int s2 = (l16 >> 3) & 1;  // v_s read-side swizzle bit
    int vput = 1, vget = 2;   // (kc+1)%3, (kc-1)%3 (vget valid from kc=1)
    for (int kc = 0; kc <= 32; ++kc) {
        int cur = kc & 1, prv = cur ^ 1;
        // commit prefetched chunk kc+1 into k_s[prv] / v_s[vput] (readers resume next window+)
        if (kc < 31) {
#pragma unroll
            for (int j = 0; j < 2; ++j) {
                *(short8*)(k_s[prv] + krow * 264 + kseg * 16 + (j ^ sk) * 8) = kst[j];
                *(short8*)(v_s[vput] + vrow * 40 + vhalf * 16 + (j ^ sv) * 8) = vst[j];
            }
        }
        // ISSUE prefetch of chunk kc+2 EARLY (ds_write above already consumed kst/vst; WAR-safe;
        // loads now have phase1+phase2 to complete before the barrier's vmcnt(0) drain)
        if (kc < 30) {
            int koff = (kc + 2) * 8192, voff = (kc + 2) * 32;
#pragma unroll
            for (int j = 0; j < 2; ++j) {
                kst[j] = *(const short8*)(kbase + koff + j * 8);
                vst[j] = *(const short8*)(vbase + voff + j * 8);
            }
        }
        // phase 1 (kc<32): S^T[kt*16..][pp*32..] on chunk kc; write P[kc] -> p_s[cur]
        if (kc < 32) {
            floatx4 cc0 = (floatx4){0.f, 0.f, 0.f, 0.f};
            floatx4 cc1 = (floatx4){0.f, 0.f, 0.f, 0.f};
            const short* krd = k_s[cur] + (kt * 16 + l16) * 264;
            __builtin_amdgcn_s_setprio(1);
#pragma unroll
            for (int fs = 0; fs < 8; ++fs) {
                short8 a = *(const short8*)(krd + fs * 32 + (quad ^ ((fs >> 1) & 1)) * 8);
                cc0 = __builtin_amdgcn_mfma_f32_16x16x32_bf16(a, qf[0][fs], cc0, 0, 0, 0);
                cc1 = __builtin_amdgcn_mfma_f32_16x16x32_bf16(a, qf[1][fs], cc1, 0, 0, 0);
            }
            __builtin_amdgcn_s_setprio(0);
            // |s|<=1: plain exp; P row cols kt*16+quad*4..+3
            float e0 = __expf(cc0[0]), e1 = __expf(cc0[1]);
            float e2 = __expf(cc0[2]), e3 = __expf(cc0[3]);
            dacc0 += (e0 + e1) + (e2 + e3);
            uintx2 w0; w0[0] = cvtpk_bf16(e0, e1); w0[1] = cvtpk_bf16(e2, e3);
            *(uintx2*)(p_s[cur] + (pp * 32 + l16) * 40 + kt * 16 + quad * 4) = w0;
            float f0 = __expf(cc1[0]), f1 = __expf(cc1[1]);
            float f2 = __expf(cc1[2]), f3 = __expf(cc1[3]);
            dacc1 += (f0 + f1) + (f2 + f3);
            uintx2 w1; w1[0] = cvtpk_bf16(f0, f1); w1[1] = cvtpk_bf16(f2, f3);
            *(uintx2*)(p_s[cur] + (pp * 32 + 16 + l16) * 40 + kt * 16 + quad * 4) = w1;
        }
        // phase 2 (kc>=1): out^T += V[kc-1]^T x P[kc-1]^T ; f [fh*64,+64), p [ph*64,+64)
        if (kc > 0) {
            short8 av[4];
#pragma unroll
            for (int fl = 0; fl < 4; ++fl)
                av[fl] = *(const short8*)(v_s[vget] + (fh * 64 + fl * 16 + l16) * 40 + (quad ^ s2) * 8);
            __builtin_amdgcn_s_setprio(1);
#pragma unroll
            for (int p2 = 0; p2 < 4; ++p2) {
                short8 bq = *(const short8*)(p_s[prv] + (ph * 64 + p2 * 16 + l16) * 40 + quad * 8);
#pragma unroll
                for (int fl = 0; fl < 4; ++fl)
                    acc[p2][fl] = __builtin_amdgcn_mfma_f32_16x16x32_bf16(av[fl], bq, acc[p2][fl], 0, 0, 0);
            }
            __builtin_amdgcn_s_setprio(0);
        }
        __syncthreads();   // the ONE barrier: all this window's LDS writes visible next window
        vput = (vput == 2) ? 0 : vput + 1;
        vget = (vget == 2) ? 0 : vget + 1;
    }
    // denominators: quad-reduce within wave, combine the two kt halves via LDS
    dacc0 += __shfl_xor(dacc0, 16); dacc0 += __shfl_xor(dacc0, 32);
    dacc1 += __shfl_xor(dacc1, 16); dacc1 += __shfl_xor(dacc1, 32);
    if (quad == 0) {
        dsum[kt][pp * 32 + l16] = dacc0;
        dsum[kt][pp * 32 + 16 + l16] = dacc1;
    }
    __syncthreads();
    float* ob = out + (size_t)b * 1048576 + qt * 128;
#pragma unroll
    for (int p2 = 0; p2 < 4; ++p2) {
        int pcol = ph * 64 + p2 * 16 + l16;
        float inv = 1.f / (dsum[0][pcol] + dsum[1][pcol]);
#pragma unroll
        for (int fl = 0; fl < 4; ++fl) {
            int f0 = fh * 64 + fl * 16 + quad * 4;
#pragma unroll
            for (int r = 0; r < 4; ++r)
                ob[(size_t)(f0 + r) * 4096 + pcol] = acc[p2][fl][r] * inv;
        }
    }
}

extern "C" void kernel_launch(void* const* d_in, const int* in_sizes, int n_in,
                              void* d_out, int out_size, void* d_ws, size_t ws_size,
                              hipStream_t stream) {
    (void)in_sizes; (void)n_in; (void)out_size; (void)ws_size;
    const float* x   = (const float*)d_in[0];
    const float* wqp = (const float*)d_in[1];
    const float* wkv = (const float*)d_in[2];
    float* out = (float*)d_out;

    char* ws = (char*)d_ws;
    short* qraw = (short*)ws;                          // 16 MiB, [b][p][f] normalized bf16
    short* kraw = (short*)(ws + 16777216);             // 4 MiB,  [b][p2][f] normalized bf16
    short* vraw = (short*)(ws + 16777216 + 4194304);   // 4 MiB,  [b][f][p2] bf16

    proj<<<512, 256, 0, stream>>>(x, wqp, wkv, qraw, kraw, vraw);
    attn<<<256, 512, 0, stream>>>(qraw, kraw, vraw, out);
}

// Round 13
// 175.222 us; speedup vs baseline: 2.3478x; 2.3478x over previous
//
#include <hip/hip_runtime.h>

// x(8,64,8,64,64) fp32, w_q(32,64), w_kv(64,64)
// f = d*8+n (256), p = y*64+xi (4096), p2 = y2*32+x2 (1024)

typedef __attribute__((ext_vector_type(8))) short short8;
typedef __attribute__((ext_vector_type(4))) float floatx4;
typedef __attribute__((ext_vector_type(2))) unsigned uintx2;
typedef __attribute__((ext_vector_type(4))) unsigned uintx4;

__device__ __forceinline__ short f2bf(float f) {  // RNE, finite only
    unsigned u = __builtin_bit_cast(unsigned, f);
    u += 0x7fffu + ((u >> 16) & 1u);
    return (short)(u >> 16);
}
__device__ __forceinline__ unsigned pack2bf(float a, float b) {
    return (unsigned)(unsigned short)f2bf(a) | ((unsigned)(unsigned short)f2bf(b) << 16);
}
__device__ __forceinline__ unsigned cvtpk_bf16(float lo, float hi) {
    unsigned r;
    asm("v_cvt_pk_bf16_f32 %0, %1, %2" : "=v"(r) : "v"(lo), "v"(hi));
    return r;
}

// ---------------- Fused projection: q (normalized), k (normalized), v ----------------
// R1 structure (no spill). R11: group swizzle g->dg*8+(j^dg) on q/k pack (conflicts
// 7.5e6->4.1e6, 61->54us, VERIFIED). R13 keeps R12's (C) and REVERTS R12's (D):
//  (C) q-pack dword-slot swizzle: short n stored at slot n^(xc&6) -> bank gains (xc>>1)&3 ->
//      32 distinct banks on the q-pack. Flush un-permutes dwords with out[d]=v[d^it],
//      compile-time since r>>3==it there. qraw bytes identical.
//  (D) REVERTED: persistent xreg[4] cc-prefetch -> VGPR 256 + 16KB LDS spill + 0.6GB scratch
//      (R12, 325us). Persistent reg arrays across __syncthreads are an allocator trigger
//      (same class as R4/R5). Staging loads stay between the two barriers (R1 form).
// No launch_bounds / overlay-pointer / packed-store changes (R2-R5 blowups).
// R7 note: kv MUST be gated on (y&1)==0 (::2-subsampled rows).
// grid 512 = (b, y); thread t: n=t>>5, dg=(t>>3)&3 (d=dg*8+j), xc=t&7 (xi=xc*4+i within half)
__global__ __launch_bounds__(256) void proj(const float* __restrict__ x,
                                            const float* __restrict__ wq,
                                            const float* __restrict__ wkv,
                                            short* __restrict__ qraw,
                                            short* __restrict__ kraw,
                                            short* __restrict__ vraw) {
    int b = blockIdx.x >> 6, y = blockIdx.x & 63;
    int t = threadIdx.x;
    int n = t >> 5, dg = (t >> 3) & 3, xc = t & 7;
    bool kv = (y & 1) == 0;
    int y2 = y >> 1;

    __shared__ __align__(16) float wq_s[64 * 32];   // [c][d]
    __shared__ __align__(16) float wkv_s[64 * 64];  // [c][e]
    __shared__ __align__(16) float xs[128 * 36];    // [c16*n8][32xi + pad]; overlaid by q_lds
    __shared__ __align__(16) short k_lds[16 * 264];
    __shared__ __align__(16) short v_lds[256 * 16]; // [f][xi2]
    __shared__ float red[32 * 33];
    __shared__ float nrm[32];
    short* q_lds = (short*)xs;                      // 16896 B <= 18432 B

    for (int i = t; i < 2048; i += 256) { int d = i >> 6, c = i & 63; wq_s[c * 32 + d] = wq[i]; }
    for (int i = t; i < 4096; i += 256) { int e = i >> 6, c = i & 63; wkv_s[c * 64 + e] = wkv[i]; }
    const float* xb = x + (size_t)b * 2097152 + y * 64;   // batch stride c*n*h*w
    int ns = n ^ (xc & 6);   // q-pack dword-slot swizzle (bit0 of n preserved)

    for (int xh = 0; xh < 2; ++xh) {
        float qa[8][4], ka[8][2], va[8][2];
#pragma unroll
        for (int j = 0; j < 8; ++j) {
            qa[j][0] = qa[j][1] = qa[j][2] = qa[j][3] = 0.f;
            ka[j][0] = ka[j][1] = 0.f; va[j][0] = va[j][1] = 0.f;
        }
        for (int cc = 0; cc < 4; ++cc) {
            __syncthreads();
#pragma unroll
            for (int it = 0; it < 4; ++it) {
                int i = it * 256 + t, cn = i >> 3, e = i & 7;
                float4 v = *(const float4*)(xb + (size_t)(cc * 16 + (cn >> 3)) * 32768 + (cn & 7) * 4096 + xh * 32 + e * 4);
                *(float4*)(xs + cn * 36 + e * 4) = v;
            }
            __syncthreads();
            for (int c = 0; c < 16; ++c) {
                float4 xv = *(const float4*)(xs + (c * 8 + n) * 36 + xc * 4);
                float xw[4] = {xv.x, xv.y, xv.z, xv.w};
                int cg = cc * 16 + c;
                float4 wqa = *(const float4*)(wq_s + cg * 32 + dg * 8);
                float4 wqb = *(const float4*)(wq_s + cg * 32 + dg * 8 + 4);
                float wj[8] = {wqa.x, wqa.y, wqa.z, wqa.w, wqb.x, wqb.y, wqb.z, wqb.w};
#pragma unroll
                for (int j = 0; j < 8; ++j)
#pragma unroll
                    for (int i2 = 0; i2 < 4; ++i2) qa[j][i2] += wj[j] * xw[i2];
                if (kv) {
                    float4 wka = *(const float4*)(wkv_s + cg * 64 + dg * 8);
                    float4 wkb = *(const float4*)(wkv_s + cg * 64 + dg * 8 + 4);
                    float4 wva = *(const float4*)(wkv_s + cg * 64 + 32 + dg * 8);
                    float4 wvb = *(const float4*)(wkv_s + cg * 64 + 32 + dg * 8 + 4);
                    float wk[8] = {wka.x, wka.y, wka.z, wka.w, wkb.x, wkb.y, wkb.z, wkb.w};
                    float wv2[8] = {wva.x, wva.y, wva.z, wva.w, wvb.x, wvb.y, wvb.z, wvb.w};
#pragma unroll
                    for (int j = 0; j < 8; ++j) {
                        ka[j][0] += wk[j] * xw[0]; ka[j][1] += wk[j] * xw[2];
                        va[j][0] += wv2[j] * xw[0]; va[j][1] += wv2[j] * xw[2];
                    }
                }
            }
        }
        // ---- q: row-l2norm over f, pack bf16 (group+slot swizzled) via LDS, coalesced flush ----
        __syncthreads();   // all reads of xs done (q_lds overlays xs)
#pragma unroll
        for (int i2 = 0; i2 < 4; ++i2) {
            float s = 0.f;
#pragma unroll
            for (int j = 0; j < 8; ++j) s += qa[j][i2] * qa[j][i2];
            red[(xc * 4 + i2) * 33 + n * 4 + dg] = s;
        }
        __syncthreads();
        if (t < 32) {
            float s = 0.f;
            for (int k = 0; k < 32; ++k) s += red[t * 33 + k];
            nrm[t] = 1.f / fmaxf(sqrtf(s), 1e-12f);
        }
        __syncthreads();
#pragma unroll
        for (int i2 = 0; i2 < 4; ++i2) {
            float sc = nrm[xc * 4 + i2];
#pragma unroll
            for (int j = 0; j < 8; ++j)
                q_lds[(xc * 4 + i2) * 264 + (dg * 8 + (j ^ dg)) * 8 + ns] = f2bf(qa[j][i2] * sc);
        }
        __syncthreads();
        {
            size_t qg = ((size_t)b * 4096 + y * 64 + xh * 32) * 256;
#pragma unroll
            for (int it = 0; it < 4; ++it) {
                int r = it * 8 + (t >> 5), sg = t & 31;
                uintx4 v = *(const uintx4*)(q_lds + r * 264 + (sg ^ ((sg >> 3) & 3)) * 8);
                uintx4 o;   // un-permute dwords: LDS dword d holds original d^c2, c2=(r>>3)&3==it
                o[0] = v[0 ^ it]; o[1] = v[1 ^ it]; o[2] = v[2 ^ it]; o[3] = v[3 ^ it];
                *(uintx4*)(qraw + qg + (size_t)r * 256 + sg * 8) = o;
            }
        }
        // ---- k (col-l2norm over f) and v ----
        if (kv) {
            __syncthreads();
#pragma unroll
            for (int ii = 0; ii < 2; ++ii) {
                float s = 0.f;
#pragma unroll
                for (int j = 0; j < 8; ++j) s += ka[j][ii] * ka[j][ii];
                red[(xc * 2 + ii) * 33 + n * 4 + dg] = s;
            }
            __syncthreads();
            if (t < 16) {
                float s = 0.f;
                for (int k = 0; k < 32; ++k) s += red[t * 33 + k];
                nrm[t] = 1.f / fmaxf(sqrtf(s), 1e-12f);
            }
            __syncthreads();
#pragma unroll
            for (int ii = 0; ii < 2; ++ii) {
                float sc = nrm[xc * 2 + ii];
#pragma unroll
                for (int j = 0; j < 8; ++j) {
                    int f = (dg * 8 + j) * 8 + n;
                    k_lds[(xc * 2 + ii) * 264 + (dg * 8 + (j ^ dg)) * 8 + n] = f2bf(ka[j][ii] * sc);
                    v_lds[f * 16 + xc * 2 + ii] = f2bf(va[j][ii]);
                }
            }
            __syncthreads();
            size_t kg = ((size_t)b * 1024 + y2 * 32 + xh * 16) * 256;
#pragma unroll
            for (int it = 0; it < 2; ++it) {
                int r = it * 8 + (t >> 5), sg = t & 31;
                *(uint4*)(kraw + kg + (size_t)r * 256 + sg * 8) =
                    *(const uint4*)(k_lds + r * 264 + (sg ^ ((sg >> 3) & 3)) * 8);
            }
            size_t vg = (size_t)b * 262144 + (size_t)y2 * 32 + xh * 16;
#pragma unroll
            for (int it = 0; it < 2; ++it) {
                int idx = it * 256 + t, f = idx >> 1, hh = idx & 1;
                *(uint4*)(vraw + vg + (size_t)f * 1024 + hh * 8) = *(const uint4*)(v_lds + f * 16 + hh * 8);
            }
        }
    }
}

// ---------------- attn: qtile=128, 8 waves; P software-pipelined, ONE barrier/kc ----------------
// R9 text (best measured attn). Window: commit(kc+1) -> issue prefetch(kc+2) -> phase1(kc) ->
// phase2(kc-1) -> barrier; prefetch loads get phase1+phase2 (~3K cy) to land before the
// barrier's vmcnt(0) drain. v_s triple-buffered; k_s/p_s double. XCD swizzle b=bid&7.
// grid 256 = (b, qt of 128 rows), 512 threads; LDS ~114KB, 1 block/CU.
// phase1: wave (kt=wv&1, pp=wv>>1): S^T rows kt*16..+16, cols pp*32..+32
// phase2: wave (fh=wv&3, ph=wv>>2): out^T f [fh*64,+64), p [ph*64,+64)
// LDS col-slot swizzles (write and read sides must match):
//   k_s: slot c=fs*4+quad stored at c^((c>>3)&1)  (write: j^((kseg>>2)&1))
//   v_s: slot quad stored at quad^((row>>3)&1)    (write: j^((t>>4)&1))
__global__ __launch_bounds__(512, 2) void attn(const short* __restrict__ qraw,
                                               const short* __restrict__ kraw,
                                               const short* __restrict__ vraw,
                                               float* __restrict__ out) {
    int b = blockIdx.x & 7, qt = blockIdx.x >> 3;   // XCD swizzle: batch pinned to one XCD
    int t = threadIdx.x, wv = t >> 6, lane = t & 63, l16 = lane & 15, quad = lane >> 4;

    __shared__ __align__(16) short k_s[2][32 * 264];  // [kp][f]+pad, 2x16.9KB
    __shared__ __align__(16) short v_s[3][256 * 40];  // [f][kp]+pad, 3x20.5KB (triple: see hdr)
    __shared__ __align__(16) short p_s[2][128 * 40];  // [p][kp]+pad, 2x10.25KB
    __shared__ float dsum[2][128];

    int kt = wv & 1, pp = wv >> 1;    // phase-1 role
    int fh = wv & 3, ph = wv >> 2;    // phase-2 role

    // Q fragments (prenormalized): wave's phase-1 p = qt*128 + pp*32 + pt*16 + l16
    short8 qf[2][8];
    const short* qb = qraw + ((size_t)b * 4096 + qt * 128 + pp * 32) * 256;
#pragma unroll
    for (int pt = 0; pt < 2; ++pt)
#pragma unroll
        for (int fs = 0; fs < 8; ++fs)
            qf[pt][fs] = *(const short8*)(qb + (pt * 16 + l16) * 256 + fs * 32 + quad * 8);

    floatx4 acc[4][4];  // [p-tile of 16 within ph*64][f-tile of 16 within fh*64]
#pragma unroll
    for (int i = 0; i < 4; ++i)
#pragma unroll
        for (int j = 0; j < 4; ++j) acc[i][j] = (floatx4){0.f, 0.f, 0.f, 0.f};
    float dacc0 = 0.f, dacc1 = 0.f;

    // staging: K chunk 32x256, V chunk 256x32, 16 shorts (2 x b128) per thread each
    int krow = t >> 4, kseg = t & 15;
    int vrow = t >> 1, vhalf = t & 1;
    int sk = (kseg >> 2) & 1, sv = (t >> 4) & 1;
    const short* kbase = kraw + ((size_t)b * 1024 + krow) * 256 + kseg * 16;
    const short* vbase = vraw + ((size_t)b * 256 + vrow) * 1024 + vhalf * 16;

    short8 kst[2], vst[2];
    // stage chunk 0 into k_s[0]/v_s[0] (with swizzle)
#pragma unroll
    for (int j = 0; j < 2; ++j) {
        kst[j] = *(const short8*)(kbase + j * 8);
        vst[j] = *(const short8*)(vbase + j * 8);
    }
#pragma unroll
    for (int j = 0; j < 2; ++j) {
        *(short8*)(k_s[0] + krow * 264 + kseg * 16 + (j ^ sk) * 8) = kst[j];
        *(short8*)(v_s[0] + vrow * 40 + vhalf * 16 + (j ^ sv) * 8) = vst[j];
    }
    // prefetch chunk 1 into regs
#pragma unroll
    for (int j = 0; j < 2; ++j) {
        kst[j] = *(const short8*)(kbase + 8192 + j * 8);
        vst[j] = *(const short8*)(vbase + 32 + j * 8);
    }
    __syncthreads();

    int s2 = (l16 >> 3) & 1;  // v_s read-side swizzle bit
    int vput = 1, vget = 2;   // (kc+1)%3, (kc-1)%3 (vget valid from kc=1)
    for (int kc = 0; kc <= 32; ++kc) {
        int cur = kc & 1, prv = cur ^ 1;
        // commit prefetched chunk kc+1 into k_s[prv] / v_s[vput] (readers resume next window+)
        if (kc < 31) {
#pragma unroll
            for (int j = 0; j < 2; ++j) {
                *(short8*)(k_s[prv] + krow * 264 + kseg * 16 + (j ^ sk) * 8) = kst[j];
                *(short8*)(v_s[vput] + vrow * 40 + vhalf * 16 + (j ^ sv) * 8) = vst[j];
            }
        }
        // ISSUE prefetch of chunk kc+2 EARLY (ds_write above already consumed kst/vst; WAR-safe;
        // loads now have phase1+phase2 to complete before the barrier's vmcnt(0) drain)
        if (kc < 30) {
            int koff = (kc + 2) * 8192, voff = (kc + 2) * 32;
#pragma unroll
            for (int j = 0; j < 2; ++j) {
                kst[j] = *(const short8*)(kbase + koff + j * 8);
                vst[j] = *(const short8*)(vbase + voff + j * 8);
            }
        }
        // phase 1 (kc<32): S^T[kt*16..][pp*32..] on chunk kc; write P[kc] -> p_s[cur]
        if (kc < 32) {
            floatx4 cc0 = (floatx4){0.f, 0.f, 0.f, 0.f};
            floatx4 cc1 = (floatx4){0.f, 0.f, 0.f, 0.f};
            const short* krd = k_s[cur] + (kt * 16 + l16) * 264;
            __builtin_amdgcn_s_setprio(1);
#pragma unroll
            for (int fs = 0; fs < 8; ++fs) {
                short8 a = *(const short8*)(krd + fs * 32 + (quad ^ ((fs >> 1) & 1)) * 8);
                cc0 = __builtin_amdgcn_mfma_f32_16x16x32_bf16(a, qf[0][fs], cc0, 0, 0, 0);
                cc1 = __builtin_amdgcn_mfma_f32_16x16x32_bf16(a, qf[1][fs], cc1, 0, 0, 0);
            }
            __builtin_amdgcn_s_setprio(0);
            // |s|<=1: plain exp; P row cols kt*16+quad*4..+3
            float e0 = __expf(cc0[0]), e1 = __expf(cc0[1]);
            float e2 = __expf(cc0[2]), e3 = __expf(cc0[3]);
            dacc0 += (e0 + e1) + (e2 + e3);
            uintx2 w0; w0[0] = cvtpk_bf16(e0, e1); w0[1] = cvtpk_bf16(e2, e3);
            *(uintx2*)(p_s[cur] + (pp * 32 + l16) * 40 + kt * 16 + quad * 4) = w0;
            float f0 = __expf(cc1[0]), f1 = __expf(cc1[1]);
            float f2 = __expf(cc1[2]), f3 = __expf(cc1[3]);
            dacc1 += (f0 + f1) + (f2 + f3);
            uintx2 w1; w1[0] = cvtpk_bf16(f0, f1); w1[1] = cvtpk_bf16(f2, f3);
            *(uintx2*)(p_s[cur] + (pp * 32 + 16 + l16) * 40 + kt * 16 + quad * 4) = w1;
        }
        // phase 2 (kc>=1): out^T += V[kc-1]^T x P[kc-1]^T ; f [fh*64,+64), p [ph*64,+64)
        if (kc > 0) {
            short8 av[4];
#pragma unroll
            for (int fl = 0; fl < 4; ++fl)
                av[fl] = *(const short8*)(v_s[vget] + (fh * 64 + fl * 16 + l16) * 40 + (quad ^ s2) * 8);
            __builtin_amdgcn_s_setprio(1);
#pragma unroll
            for (int p2 = 0; p2 < 4; ++p2) {
                short8 bq = *(const short8*)(p_s[prv] + (ph * 64 + p2 * 16 + l16) * 40 + quad * 8);
#pragma unroll
                for (int fl = 0; fl < 4; ++fl)
                    acc[p2][fl] = __builtin_amdgcn_mfma_f32_16x16x32_bf16(av[fl], bq, acc[p2][fl], 0, 0, 0);
            }
            __builtin_amdgcn_s_setprio(0);
        }
        __syncthreads();   // the ONE barrier: all this window's LDS writes visible next window
        vput = (vput == 2) ? 0 : vput + 1;
        vget = (vget == 2) ? 0 : vget + 1;
    }
    // denominators: quad-reduce within wave, combine the two kt halves via LDS
    dacc0 += __shfl_xor(dacc0, 16); dacc0 += __shfl_xor(dacc0, 32);
    dacc1 += __shfl_xor(dacc1, 16); dacc1 += __shfl_xor(dacc1, 32);
    if (quad == 0) {
        dsum[kt][pp * 32 + l16] = dacc0;
        dsum[kt][pp * 32 + 16 + l16] = dacc1;
    }
    __syncthreads();
    float* ob = out + (size_t)b * 1048576 + qt * 128;
#pragma unroll
    for (int p2 = 0; p2 < 4; ++p2) {
        int pcol = ph * 64 + p2 * 16 + l16;
        float inv = 1.f / (dsum[0][pcol] + dsum[1][pcol]);
#pragma unroll
        for (int fl = 0; fl < 4; ++fl) {
            int f0 = fh * 64 + fl * 16 + quad * 4;
#pragma unroll
            for (int r = 0; r < 4; ++r)
                ob[(size_t)(f0 + r) * 4096 + pcol] = acc[p2][fl][r] * inv;
        }
    }
}

extern "C" void kernel_launch(void* const* d_in, const int* in_sizes, int n_in,
                              void* d_out, int out_size, void* d_ws, size_t ws_size,
                              hipStream_t stream) {
    (void)in_sizes; (void)n_in; (void)out_size; (void)ws_size;
    const float* x   = (const float*)d_in[0];
    const float* wqp = (const float*)d_in[1];
    const float* wkv = (const float*)d_in[2];
    float* out = (float*)d_out;

    char* ws = (char*)d_ws;
    short* qraw = (short*)ws;                          // 16 MiB, [b][p][f] normalized bf16
    short* kraw = (short*)(ws + 16777216);             // 4 MiB,  [b][p2][f] normalized bf16
    short* vraw = (short*)(ws + 16777216 + 4194304);   // 4 MiB,  [b][f][p2] bf16

    proj<<<512, 256, 0, stream>>>(x, wqp, wkv, qraw, kraw, vraw);
    attn<<<256, 512, 0, stream>>>(qraw, kraw, vraw, out);
}